// Round 6
// baseline (1303.427 us; speedup 1.0000x reference)
//
#include <hip/hip_runtime.h>
#include <hip/hip_bf16.h>

#define NEXP 5

typedef unsigned short u16;
typedef __attribute__((ext_vector_type(8))) short bf16x8;
typedef __attribute__((ext_vector_type(4))) float f32x4;
typedef __attribute__((ext_vector_type(4))) unsigned short u16x4;

__device__ inline u16 f2bf(float v) {
  __hip_bfloat16 b = __float2bfloat16(v);
  return *reinterpret_cast<u16*>(&b);
}
__device__ inline float bf2f(u16 u) {
  __hip_bfloat16 b = *reinterpret_cast<__hip_bfloat16*>(&u);
  return __bfloat162float(b);
}

// m204 bijective XCD swizzle: contiguous chunk of the (compact) grid per XCD
__device__ inline int xcd_swz(int orig, int nwg) {
  const int q = nwg >> 3, r = nwg & 7;
  const int x = orig & 7;
  const int i = orig >> 3;
  return (x < r ? x * (q + 1) : r * (q + 1) + (x - r) * q) + i;
}

// ---------------- Expert bucketing ----------------
__global__ void count_kernel(const int* __restrict__ code, int* __restrict__ cnt, int T) {
  const int t = blockIdx.x * blockDim.x + threadIdx.x;
  if (t < T) atomicAdd(&cnt[code[t]], 1);
}

// offsets + compact tile table: tab[i] = (e<<16)|mtile, ntiles = total m-tiles
__global__ void offsets_kernel(const int* __restrict__ cnt, int* __restrict__ off,
                               int* __restrict__ ntiles, int* __restrict__ tab) {
  if (threadIdx.x == 0) {
    int a = 0, n = 0;
    for (int e = 0; e < NEXP; ++e) {
      off[e] = a;
      a += cnt[e];
      const int mt = (cnt[e] + 127) >> 7;
      for (int m = 0; m < mt; ++m) tab[n++] = (e << 16) | m;
    }
    *ntiles = n;
  }
}

// also records rank[t]: the sorted row this token lands in
__global__ void scatter_kernel(const int* __restrict__ code, const int* __restrict__ off,
                               int* __restrict__ fill, int* __restrict__ list,
                               int* __restrict__ rank, int T) {
  const int t = blockIdx.x * blockDim.x + threadIdx.x;
  if (t < T) {
    const int c = code[t];
    const int p = atomicAdd(&fill[c], 1);
    const int r = off[c] + p;
    list[r] = t;
    rank[t] = r;
  }
}

// ---------------- LayerNorm: one block per token, writes h (hi/lo bf16) at SORTED row ----------------
__global__ void ln_kernel(const float* __restrict__ x,
                          const float* __restrict__ gamma,
                          const float* __restrict__ beta,
                          const int* __restrict__ rank,
                          u16* __restrict__ hh, u16* __restrict__ hl, int D) {
  const int t = blockIdx.x;
  const int tid = threadIdx.x;  // D/4 = 256 threads
  const float4 v = reinterpret_cast<const float4*>(x + (size_t)t * D)[tid];
  float s = v.x + v.y + v.z + v.w;
  float ss = v.x * v.x + v.y * v.y + v.z * v.z + v.w * v.w;
#pragma unroll
  for (int o = 32; o > 0; o >>= 1) {
    s += __shfl_down(s, o);
    ss += __shfl_down(ss, o);
  }
  __shared__ float red_s[4], red_ss[4];
  const int wid = tid >> 6;
  if ((tid & 63) == 0) { red_s[wid] = s; red_ss[wid] = ss; }
  __syncthreads();
  const float tot  = red_s[0] + red_s[1] + red_s[2] + red_s[3];
  const float tot2 = red_ss[0] + red_ss[1] + red_ss[2] + red_ss[3];
  const float mu = tot / (float)D;
  const float var = tot2 / (float)D - mu * mu;
  const float rs = rsqrtf(var + 1e-6f);
  const float4 g = reinterpret_cast<const float4*>(gamma)[tid];
  const float4 b = reinterpret_cast<const float4*>(beta)[tid];
  float o[4];
  o[0] = (v.x - mu) * rs * g.x + b.x;
  o[1] = (v.y - mu) * rs * g.y + b.y;
  o[2] = (v.z - mu) * rs * g.z + b.z;
  o[3] = (v.w - mu) * rs * g.w + b.w;
  u16x4 hv, lv;
#pragma unroll
  for (int j = 0; j < 4; ++j) {
    const u16 hi = f2bf(o[j]);
    hv[j] = hi;
    lv[j] = f2bf(o[j] - bf2f(hi));
  }
  const size_t row = (size_t)rank[t] * D;
  reinterpret_cast<u16x4*>(hh + row)[tid] = hv;
  reinterpret_cast<u16x4*>(hl + row)[tid] = lv;
}

// ---------------- Transpose + split: in [R][C] fp32 -> out [C][R] bf16 hi/lo ----------------
__global__ void transpose_split_kernel(const float* __restrict__ in,
                                       u16* __restrict__ oh, u16* __restrict__ ol,
                                       int R, int C) {
  __shared__ float tile[32][33];
  const int tx = threadIdx.x, ty = threadIdx.y;  // (32,8)
  const int x0 = blockIdx.x * 32, y0 = blockIdx.y * 32;
#pragma unroll
  for (int i = ty; i < 32; i += 8)
    tile[i][tx] = in[(size_t)(y0 + i) * C + x0 + tx];
  __syncthreads();
#pragma unroll
  for (int i = ty; i < 32; i += 8) {
    const float v = tile[tx][i];
    const u16 hi = f2bf(v);
    const u16 lo = f2bf(v - bf2f(hi));
    const size_t o = (size_t)(x0 + i) * R + y0 + tx;
    oh[o] = hi;
    ol[o] = lo;
  }
}

// ---------------- Grouped bf16x3 MFMA GEMM1 ----------------
// inter[sorted] = relu(h_sorted @ W1T_e^T + b1_e), bf16 hi (+lo if USE_IL).
// Compact 1D grid over (tile-table x n-blocks), XCD-swizzled.
// A-frags read DIRECTLY from global (L2-resident; 16x64B per wave-read);
// B staged in LDS. Tile 128x128, BK=32, 4 waves 2x2, 4x4 frags of 16x16x32.
template <bool USE_IL>
__global__ __launch_bounds__(256, 3)
void gemm1_kernel(const u16* __restrict__ hh, const u16* __restrict__ hl,
                  const u16* __restrict__ wth, const u16* __restrict__ wtl,
                  const float* __restrict__ b1,
                  u16* __restrict__ ih, u16* __restrict__ il,
                  const int* __restrict__ cnt, const int* __restrict__ off,
                  const int* __restrict__ ntiles, const int* __restrict__ tab,
                  int D, int F, int gxl, int nwg) {
  const int f = xcd_swz(blockIdx.x, nwg);
  const int tile = f >> gxl;
  if (tile >= *ntiles) return;
  const int te = tab[tile];
  const int e = te >> 16;
  const int m0 = (te & 0xffff) << 7;
  const int n0 = (f & ((1 << gxl) - 1)) << 7;
  const int count = cnt[e];
  const int base = off[e];
  const int tid = threadIdx.x;

  __shared__ u16 Bh[128][40];  // [n][k], row stride 80B
  __shared__ u16 Bl[128][40];

  const int srow = tid >> 2;       // 0..63 (rows srow, srow+64)
  const int sp8 = (tid & 3) * 8;   // 16B segment
  const size_t bn0 = (size_t)e * F + n0;  // global row in W1T [5F][D]

  const u16* pBh0 = wth + (bn0 + srow) * (size_t)D + sp8;
  const u16* pBh1 = wth + (bn0 + srow + 64) * (size_t)D + sp8;
  const u16* pBl0 = wtl + (bn0 + srow) * (size_t)D + sp8;
  const u16* pBl1 = wtl + (bn0 + srow + 64) * (size_t)D + sp8;

  const int lane = tid & 63;
  const int wid = tid >> 6;
  const int wm = wid >> 1, wn = wid & 1;
  const int lr = lane & 15, lg = lane >> 4;

  // A-frag per-lane global pointers: row = m-frag row + lr, k-slice = lg*8
  const u16* pAh[4];
  const u16* pAl[4];
#pragma unroll
  for (int m = 0; m < 4; ++m) {
    const size_t r = (size_t)(base + min(m0 + wm * 64 + m * 16 + lr, count - 1));
    pAh[m] = hh + r * D + lg * 8;
    pAl[m] = hl + r * D + lg * 8;
  }

  int boff[4];
#pragma unroll
  for (int n = 0; n < 4; ++n) boff[n] = (wn * 64 + n * 16 + lr) * 40 + lg * 8;

  f32x4 acc[4][4];
#pragma unroll
  for (int m = 0; m < 4; ++m)
#pragma unroll
    for (int n = 0; n < 4; ++n) acc[m][n] = (f32x4){0.f, 0.f, 0.f, 0.f};

  // prologue: B K-tile 0 into registers
  bf16x8 rBh0 = *(const bf16x8*)(pBh0), rBh1 = *(const bf16x8*)(pBh1);
  bf16x8 rBl0 = *(const bf16x8*)(pBl0), rBl1 = *(const bf16x8*)(pBl1);

  for (int k0 = 0; k0 < D; k0 += 32) {
    // A-frags for this K-tile straight from global (L2-hot); waited at first MFMA use
    bf16x8 ah[4], al[4];
#pragma unroll
    for (int m = 0; m < 4; ++m) {
      ah[m] = *(const bf16x8*)(pAh[m] + k0);
      al[m] = *(const bf16x8*)(pAl[m] + k0);
    }

    __syncthreads();  // prev tile's B reads done
    *(bf16x8*)&Bh[srow][sp8] = rBh0;  *(bf16x8*)&Bh[srow + 64][sp8] = rBh1;
    *(bf16x8*)&Bl[srow][sp8] = rBl0;  *(bf16x8*)&Bl[srow + 64][sp8] = rBl1;
    __syncthreads();

    const int kn = k0 + 32;
    if (kn < D) {  // prefetch next B tile; latency hides under MFMA
      rBh0 = *(const bf16x8*)(pBh0 + kn);  rBh1 = *(const bf16x8*)(pBh1 + kn);
      rBl0 = *(const bf16x8*)(pBl0 + kn);  rBl1 = *(const bf16x8*)(pBl1 + kn);
    }

    bf16x8 bh[4], bl[4];
#pragma unroll
    for (int n = 0; n < 4; ++n) {
      bh[n] = *reinterpret_cast<const bf16x8*>(&Bh[0][0] + boff[n]);
      bl[n] = *reinterpret_cast<const bf16x8*>(&Bl[0][0] + boff[n]);
    }
#pragma unroll
    for (int m = 0; m < 4; ++m)
#pragma unroll
      for (int n = 0; n < 4; ++n) {
        acc[m][n] = __builtin_amdgcn_mfma_f32_16x16x32_bf16(ah[m], bh[n], acc[m][n], 0, 0, 0);
        acc[m][n] = __builtin_amdgcn_mfma_f32_16x16x32_bf16(ah[m], bl[n], acc[m][n], 0, 0, 0);
        acc[m][n] = __builtin_amdgcn_mfma_f32_16x16x32_bf16(al[m], bh[n], acc[m][n], 0, 0, 0);
      }
  }

  // epilogue: relu(acc + b1) -> split -> inter (sorted rows)
#pragma unroll
  for (int n = 0; n < 4; ++n) {
    const int gcol = n0 + wn * 64 + n * 16 + lr;
    const float bias = b1[(size_t)e * F + gcol];
#pragma unroll
    for (int m = 0; m < 4; ++m) {
#pragma unroll
      for (int j = 0; j < 4; ++j) {
        const int lm = m0 + wm * 64 + m * 16 + lg * 4 + j;
        if (lm >= count) continue;
        const float v = fmaxf(acc[m][n][j] + bias, 0.f);
        const u16 hi = f2bf(v);
        const size_t o = (size_t)(base + lm) * F + gcol;
        ih[o] = hi;
        if constexpr (USE_IL) il[o] = f2bf(v - bf2f(hi));
      }
    }
  }
}

// ---------------- Grouped bf16x3 MFMA GEMM2 ----------------
// out[t] = inter_sorted @ W2T_e^T + b2_e + x[t]; A (inter) direct-from-global.
template <bool USE_IL>
__global__ __launch_bounds__(256, 3)
void gemm2_kernel(const u16* __restrict__ ih, const u16* __restrict__ il,
                  const u16* __restrict__ wth, const u16* __restrict__ wtl,
                  const float* __restrict__ b2, const float* __restrict__ x,
                  float* __restrict__ out,
                  const int* __restrict__ cnt, const int* __restrict__ off,
                  const int* __restrict__ list,
                  const int* __restrict__ ntiles, const int* __restrict__ tab,
                  int D, int F, int gxl, int nwg) {
  const int f = xcd_swz(blockIdx.x, nwg);
  const int tile = f >> gxl;
  if (tile >= *ntiles) return;
  const int te = tab[tile];
  const int e = te >> 16;
  const int m0 = (te & 0xffff) << 7;
  const int n0 = (f & ((1 << gxl) - 1)) << 7;
  const int count = cnt[e];
  const int base = off[e];
  const int tid = threadIdx.x;

  __shared__ u16 Bh[128][40];
  __shared__ u16 Bl[128][40];

  const int srow = tid >> 2;
  const int sp8 = (tid & 3) * 8;
  const size_t bn0 = (size_t)e * D + n0;  // global row in W2T [5D][F]

  const u16* pBh0 = wth + (bn0 + srow) * (size_t)F + sp8;
  const u16* pBh1 = wth + (bn0 + srow + 64) * (size_t)F + sp8;
  const u16* pBl0 = wtl + (bn0 + srow) * (size_t)F + sp8;
  const u16* pBl1 = wtl + (bn0 + srow + 64) * (size_t)F + sp8;

  const int lane = tid & 63;
  const int wid = tid >> 6;
  const int wm = wid >> 1, wn = wid & 1;
  const int lr = lane & 15, lg = lane >> 4;

  const u16* pAh[4];
  const u16* pAl[4];
#pragma unroll
  for (int m = 0; m < 4; ++m) {
    const size_t r = (size_t)(base + min(m0 + wm * 64 + m * 16 + lr, count - 1));
    pAh[m] = ih + r * F + lg * 8;
    pAl[m] = il + r * F + lg * 8;
  }

  int boff[4];
#pragma unroll
  for (int n = 0; n < 4; ++n) boff[n] = (wn * 64 + n * 16 + lr) * 40 + lg * 8;

  f32x4 acc[4][4];
#pragma unroll
  for (int m = 0; m < 4; ++m)
#pragma unroll
    for (int n = 0; n < 4; ++n) acc[m][n] = (f32x4){0.f, 0.f, 0.f, 0.f};

  bf16x8 rBh0 = *(const bf16x8*)(pBh0), rBh1 = *(const bf16x8*)(pBh1);
  bf16x8 rBl0 = *(const bf16x8*)(pBl0), rBl1 = *(const bf16x8*)(pBl1);

  for (int k0 = 0; k0 < F; k0 += 32) {
    bf16x8 ah[4], al[4];
#pragma unroll
    for (int m = 0; m < 4; ++m) {
      ah[m] = *(const bf16x8*)(pAh[m] + k0);
      if constexpr (USE_IL) al[m] = *(const bf16x8*)(pAl[m] + k0);
    }

    __syncthreads();
    *(bf16x8*)&Bh[srow][sp8] = rBh0;  *(bf16x8*)&Bh[srow + 64][sp8] = rBh1;
    *(bf16x8*)&Bl[srow][sp8] = rBl0;  *(bf16x8*)&Bl[srow + 64][sp8] = rBl1;
    __syncthreads();

    const int kn = k0 + 32;
    if (kn < F) {
      rBh0 = *(const bf16x8*)(pBh0 + kn);  rBh1 = *(const bf16x8*)(pBh1 + kn);
      rBl0 = *(const bf16x8*)(pBl0 + kn);  rBl1 = *(const bf16x8*)(pBl1 + kn);
    }

    bf16x8 bh[4], bl[4];
#pragma unroll
    for (int n = 0; n < 4; ++n) {
      bh[n] = *reinterpret_cast<const bf16x8*>(&Bh[0][0] + boff[n]);
      bl[n] = *reinterpret_cast<const bf16x8*>(&Bl[0][0] + boff[n]);
    }
#pragma unroll
    for (int m = 0; m < 4; ++m)
#pragma unroll
      for (int n = 0; n < 4; ++n) {
        acc[m][n] = __builtin_amdgcn_mfma_f32_16x16x32_bf16(ah[m], bh[n], acc[m][n], 0, 0, 0);
        acc[m][n] = __builtin_amdgcn_mfma_f32_16x16x32_bf16(ah[m], bl[n], acc[m][n], 0, 0, 0);
        if constexpr (USE_IL)
          acc[m][n] = __builtin_amdgcn_mfma_f32_16x16x32_bf16(al[m], bh[n], acc[m][n], 0, 0, 0);
      }
  }

  int trow[4][4];
#pragma unroll
  for (int m = 0; m < 4; ++m)
#pragma unroll
    for (int j = 0; j < 4; ++j) {
      const int lm = m0 + wm * 64 + m * 16 + lg * 4 + j;
      trow[m][j] = (lm < count) ? list[base + lm] : -1;
    }

#pragma unroll
  for (int n = 0; n < 4; ++n) {
    const int gcol = n0 + wn * 64 + n * 16 + lr;
    const float bias = b2[(size_t)e * D + gcol];
#pragma unroll
    for (int m = 0; m < 4; ++m) {
#pragma unroll
      for (int j = 0; j < 4; ++j) {
        const int t = trow[m][j];
        if (t < 0) continue;
        const size_t o = (size_t)t * D + gcol;
        out[o] = acc[m][n][j] + bias + x[o];
      }
    }
  }
}

extern "C" void kernel_launch(void* const* d_in, const int* in_sizes, int n_in,
                              void* d_out, int out_size, void* d_ws, size_t ws_size,
                              hipStream_t stream) {
  const float* x     = (const float*)d_in[0];
  const int*   code  = (const int*)d_in[1];
  const float* W1    = (const float*)d_in[2];
  const float* b1    = (const float*)d_in[3];
  const float* W2    = (const float*)d_in[4];
  const float* b2    = (const float*)d_in[5];
  const float* gamma = (const float*)d_in[6];
  const float* beta  = (const float*)d_in[7];
  const int T = in_sizes[1];
  const int D = in_sizes[6];
  const int F = in_sizes[3] / NEXP;
  float* out = (float*)d_out;

  // ws layout: [0,96B) cnt/off/fill; ntiles @96; tab @512 (<=1KiB);
  // list @4KiB, rank @256KiB (T*4 = 64KiB each);
  // wt hi @1MiB, wt lo @21MiB (20MiB each; W1T buffers reused for W2T — stream-serialized);
  // inter hi @41MiB (64MiB); inter lo @105MiB (64MiB, only if it fits).
  char* ws = (char*)d_ws;
  const size_t MiB = 1u << 20;
  int* cnt    = (int*)ws;
  int* off    = cnt + 8;
  int* fill   = cnt + 16;
  int* ntiles = (int*)(ws + 96);
  int* tab    = (int*)(ws + 512);
  int* list   = (int*)(ws + 4096);
  int* rank   = (int*)(ws + 256 * 1024);
  u16* wth = (u16*)(ws + 1 * MiB);
  u16* wtl = (u16*)(ws + 21 * MiB);
  u16* ih  = (u16*)(ws + 41 * MiB);
  u16* il  = (u16*)(ws + 105 * MiB);
  const bool use_il = ws_size >= 169 * MiB;  // fallback: bf16-hi-only inter

  // h (hi/lo bf16) lives in d_out (exactly T*D*4 B); consumed by gemm1,
  // then gemm2 overwrites d_out with the final result.
  u16* hh = (u16*)d_out;
  u16* hl = hh + (size_t)T * D;

  hipMemsetAsync(d_ws, 0, 256, stream);
  const int tb = (T + 255) / 256;
  count_kernel<<<tb, 256, 0, stream>>>(code, cnt, T);
  offsets_kernel<<<1, 64, 0, stream>>>(cnt, off, ntiles, tab);
  scatter_kernel<<<tb, 256, 0, stream>>>(code, off, fill, list, rank, T);

  ln_kernel<<<T, D / 4, 0, stream>>>(x, gamma, beta, rank, hh, hl, D);

  // W1 [D][5F] -> W1T [5F][D]
  transpose_split_kernel<<<dim3((NEXP * F) / 32, D / 32), dim3(32, 8), 0, stream>>>(
      W1, wth, wtl, D, NEXP * F);

  // Compact grids: MAXT = max possible m-tiles = ceil(T/128)+NEXP-1
  const int MAXT = (T + 127) / 128 + NEXP - 1;
  const int gx1 = F / 128, gx1l = 31 - __builtin_clz(gx1);
  const int nwg1 = MAXT * gx1;
  if (use_il)
    gemm1_kernel<true><<<nwg1, 256, 0, stream>>>(hh, hl, wth, wtl, b1, ih, il,
                                                 cnt, off, ntiles, tab, D, F, gx1l, nwg1);
  else
    gemm1_kernel<false><<<nwg1, 256, 0, stream>>>(hh, hl, wth, wtl, b1, ih, ih,
                                                  cnt, off, ntiles, tab, D, F, gx1l, nwg1);

  // W2 [F][5D] -> W2T [5D][F] (reuses W1T buffers; gemm1 already done in stream order)
  transpose_split_kernel<<<dim3((NEXP * D) / 32, F / 32), dim3(32, 8), 0, stream>>>(
      W2, wth, wtl, F, NEXP * D);

  const int gx2 = D / 128, gx2l = 31 - __builtin_clz(gx2);
  const int nwg2 = MAXT * gx2;
  if (use_il)
    gemm2_kernel<true><<<nwg2, 256, 0, stream>>>(ih, il, wth, wtl, b2, x, out,
                                                 cnt, off, list, ntiles, tab, D, F, gx2l, nwg2);
  else
    gemm2_kernel<false><<<nwg2, 256, 0, stream>>>(ih, ih, wth, wtl, b2, x, out,
                                                  cnt, off, list, ntiles, tab, D, F, gx2l, nwg2);
}

// Round 8
// 924.012 us; speedup vs baseline: 1.4106x; 1.4106x over previous
//
#include <hip/hip_runtime.h>
#include <hip/hip_bf16.h>

#define NEXP 5

typedef unsigned short u16;
typedef __attribute__((ext_vector_type(8))) short bf16x8;
typedef __attribute__((ext_vector_type(4))) float f32x4;
typedef __attribute__((ext_vector_type(4))) unsigned short u16x4;

__device__ inline u16 f2bf(float v) {
  __hip_bfloat16 b = __float2bfloat16(v);
  return *reinterpret_cast<u16*>(&b);
}
__device__ inline float bf2f(u16 u) {
  __hip_bfloat16 b = *reinterpret_cast<__hip_bfloat16*>(&u);
  return __bfloat162float(b);
}

// async global->LDS DMA, 16B per lane (wave covers base + lane*16)
__device__ inline void gload_lds16(const void* g, void* l) {
  __builtin_amdgcn_global_load_lds(
      (const __attribute__((address_space(1))) void*)g,
      (__attribute__((address_space(3))) void*)l, 16, 0, 0);
}

// m204 bijective XCD swizzle: contiguous chunk of the (compact) grid per XCD
__device__ inline int xcd_swz(int orig, int nwg) {
  const int q = nwg >> 3, r = nwg & 7;
  const int x = orig & 7;
  const int i = orig >> 3;
  return (x < r ? x * (q + 1) : r * (q + 1) + (x - r) * q) + i;
}

// ---------------- Expert bucketing ----------------
__global__ void count_kernel(const int* __restrict__ code, int* __restrict__ cnt, int T) {
  const int t = blockIdx.x * blockDim.x + threadIdx.x;
  if (t < T) atomicAdd(&cnt[code[t]], 1);
}

// offsets + compact tile table: tab[i] = (e<<16)|mtile, ntiles = total m-tiles
__global__ void offsets_kernel(const int* __restrict__ cnt, int* __restrict__ off,
                               int* __restrict__ ntiles, int* __restrict__ tab) {
  if (threadIdx.x == 0) {
    int a = 0, n = 0;
    for (int e = 0; e < NEXP; ++e) {
      off[e] = a;
      a += cnt[e];
      const int mt = (cnt[e] + 127) >> 7;
      for (int m = 0; m < mt; ++m) tab[n++] = (e << 16) | m;
    }
    *ntiles = n;
  }
}

// also records rank[t]: the sorted row this token lands in
__global__ void scatter_kernel(const int* __restrict__ code, const int* __restrict__ off,
                               int* __restrict__ fill, int* __restrict__ list,
                               int* __restrict__ rank, int T) {
  const int t = blockIdx.x * blockDim.x + threadIdx.x;
  if (t < T) {
    const int c = code[t];
    const int p = atomicAdd(&fill[c], 1);
    const int r = off[c] + p;
    list[r] = t;
    rank[t] = r;
  }
}

// ---------------- LayerNorm: one block per token, writes h (hi/lo bf16) at SORTED row ----------------
__global__ void ln_kernel(const float* __restrict__ x,
                          const float* __restrict__ gamma,
                          const float* __restrict__ beta,
                          const int* __restrict__ rank,
                          u16* __restrict__ hh, u16* __restrict__ hl, int D) {
  const int t = blockIdx.x;
  const int tid = threadIdx.x;  // D/4 = 256 threads
  const float4 v = reinterpret_cast<const float4*>(x + (size_t)t * D)[tid];
  float s = v.x + v.y + v.z + v.w;
  float ss = v.x * v.x + v.y * v.y + v.z * v.z + v.w * v.w;
#pragma unroll
  for (int o = 32; o > 0; o >>= 1) {
    s += __shfl_down(s, o);
    ss += __shfl_down(ss, o);
  }
  __shared__ float red_s[4], red_ss[4];
  const int wid = tid >> 6;
  if ((tid & 63) == 0) { red_s[wid] = s; red_ss[wid] = ss; }
  __syncthreads();
  const float tot  = red_s[0] + red_s[1] + red_s[2] + red_s[3];
  const float tot2 = red_ss[0] + red_ss[1] + red_ss[2] + red_ss[3];
  const float mu = tot / (float)D;
  const float var = tot2 / (float)D - mu * mu;
  const float rs = rsqrtf(var + 1e-6f);
  const float4 g = reinterpret_cast<const float4*>(gamma)[tid];
  const float4 b = reinterpret_cast<const float4*>(beta)[tid];
  float o[4];
  o[0] = (v.x - mu) * rs * g.x + b.x;
  o[1] = (v.y - mu) * rs * g.y + b.y;
  o[2] = (v.z - mu) * rs * g.z + b.z;
  o[3] = (v.w - mu) * rs * g.w + b.w;
  u16x4 hv, lv;
#pragma unroll
  for (int j = 0; j < 4; ++j) {
    const u16 hi = f2bf(o[j]);
    hv[j] = hi;
    lv[j] = f2bf(o[j] - bf2f(hi));
  }
  const size_t row = (size_t)rank[t] * D;
  reinterpret_cast<u16x4*>(hh + row)[tid] = hv;
  reinterpret_cast<u16x4*>(hl + row)[tid] = lv;
}

// ---------------- Transpose + split: in [R][C] fp32 -> out [C][R] bf16 hi/lo ----------------
__global__ void transpose_split_kernel(const float* __restrict__ in,
                                       u16* __restrict__ oh, u16* __restrict__ ol,
                                       int R, int C) {
  __shared__ float tile[32][33];
  const int tx = threadIdx.x, ty = threadIdx.y;  // (32,8)
  const int x0 = blockIdx.x * 32, y0 = blockIdx.y * 32;
#pragma unroll
  for (int i = ty; i < 32; i += 8)
    tile[i][tx] = in[(size_t)(y0 + i) * C + x0 + tx];
  __syncthreads();
#pragma unroll
  for (int i = ty; i < 32; i += 8) {
    const float v = tile[tx][i];
    const u16 hi = f2bf(v);
    const u16 lo = f2bf(v - bf2f(hi));
    const size_t o = (size_t)(x0 + i) * R + y0 + tx;
    oh[o] = hi;
    ol[o] = lo;
  }
}

// ---------------- Grouped bf16x3 MFMA GEMM1 (m97-style gload_lds staging) ----------------
// inter[sorted] = relu(h_sorted @ W1T_e^T + b1_e), bf16 hi (+lo if USE_IL).
// Compact 1D grid over (tile-table x n-blocks), XCD-swizzled.
// Tile 128x128, BK=32, 4 waves 2x2, 4x4 frags of 16x16x32.
// All four operand surfaces staged via async global_load_lds (16B/lane):
// per-wave LDS dest = base + lane*16 by construction (DMA requirement, m104).
template <bool USE_IL>
__global__ __launch_bounds__(256, 3)
void gemm1_kernel(const u16* __restrict__ hh, const u16* __restrict__ hl,
                  const u16* __restrict__ wth, const u16* __restrict__ wtl,
                  const float* __restrict__ b1,
                  u16* __restrict__ ih, u16* __restrict__ il,
                  const int* __restrict__ cnt, const int* __restrict__ off,
                  const int* __restrict__ ntiles, const int* __restrict__ tab,
                  int D, int F, int gxl, int nwg) {
  const int f = xcd_swz(blockIdx.x, nwg);
  const int tile = f >> gxl;
  if (tile >= *ntiles) return;
  const int te = tab[tile];
  const int e = te >> 16;
  const int m0 = (te & 0xffff) << 7;
  const int n0 = (f & ((1 << gxl) - 1)) << 7;
  const int count = cnt[e];
  const int base = off[e];
  const int tid = threadIdx.x;

  // linear layout (DMA requirement): row stride 32 u16 = 64B
  __shared__ u16 Ah[128][32];
  __shared__ u16 Al[128][32];
  __shared__ u16 Bh[128][32];
  __shared__ u16 Bl[128][32];

  const int l = tid & 63, w = tid >> 6;
  // DMA chunking: wave w, chunk c covers surface rows [(c*4+w)*16, +16)
  const int row0 = w * 16 + (l >> 2);        // chunk 0 row
  const int row1 = (4 + w) * 16 + (l >> 2);  // chunk 1 row
  const int seg = (l & 3) * 8;               // u16 offset within row (16B segs)

  // A source rows (sorted h: contiguous within expert)
  const size_t ar0 = (size_t)(base + min(m0 + row0, count - 1));
  const size_t ar1 = (size_t)(base + min(m0 + row1, count - 1));
  const size_t bn0 = (size_t)e * F + n0;  // global row in W1T [5F][D]
  const size_t br0 = (bn0 + row0) * (size_t)D;
  const size_t br1 = (bn0 + row1) * (size_t)D;

  const int lane = tid & 63;
  const int wid = tid >> 6;
  const int wm = wid >> 1, wn = wid & 1;
  const int lr = lane & 15, lg = lane >> 4;

  int aoff[4], boff[4];
#pragma unroll
  for (int m = 0; m < 4; ++m) aoff[m] = (wm * 64 + m * 16 + lr) * 32 + lg * 8;
#pragma unroll
  for (int n = 0; n < 4; ++n) boff[n] = (wn * 64 + n * 16 + lr) * 32 + lg * 8;

  f32x4 acc[4][4];
#pragma unroll
  for (int m = 0; m < 4; ++m)
#pragma unroll
    for (int n = 0; n < 4; ++n) acc[m][n] = (f32x4){0.f, 0.f, 0.f, 0.f};

  for (int k0 = 0; k0 < D; k0 += 32) {
    // issue async DMA for all 4 surfaces (8 x 16B per thread)
    gload_lds16(hh + ar0 * D + k0 + seg, &Ah[row0][seg]);
    gload_lds16(hh + ar1 * D + k0 + seg, &Ah[row1][seg]);
    gload_lds16(hl + ar0 * D + k0 + seg, &Al[row0][seg]);
    gload_lds16(hl + ar1 * D + k0 + seg, &Al[row1][seg]);
    gload_lds16(wth + br0 + k0 + seg, &Bh[row0][seg]);
    gload_lds16(wth + br1 + k0 + seg, &Bh[row1][seg]);
    gload_lds16(wtl + br0 + k0 + seg, &Bl[row0][seg]);
    gload_lds16(wtl + br1 + k0 + seg, &Bl[row1][seg]);
    __syncthreads();  // drains vmcnt -> data visible in LDS

    bf16x8 ah[4], al[4], bh[4], bl[4];
#pragma unroll
    for (int m = 0; m < 4; ++m) {
      ah[m] = *reinterpret_cast<const bf16x8*>(&Ah[0][0] + aoff[m]);
      al[m] = *reinterpret_cast<const bf16x8*>(&Al[0][0] + aoff[m]);
    }
#pragma unroll
    for (int n = 0; n < 4; ++n) {
      bh[n] = *reinterpret_cast<const bf16x8*>(&Bh[0][0] + boff[n]);
      bl[n] = *reinterpret_cast<const bf16x8*>(&Bl[0][0] + boff[n]);
    }
#pragma unroll
    for (int m = 0; m < 4; ++m)
#pragma unroll
      for (int n = 0; n < 4; ++n) {
        acc[m][n] = __builtin_amdgcn_mfma_f32_16x16x32_bf16(ah[m], bh[n], acc[m][n], 0, 0, 0);
        acc[m][n] = __builtin_amdgcn_mfma_f32_16x16x32_bf16(ah[m], bl[n], acc[m][n], 0, 0, 0);
        acc[m][n] = __builtin_amdgcn_mfma_f32_16x16x32_bf16(al[m], bh[n], acc[m][n], 0, 0, 0);
      }
    __syncthreads();  // frag reads done before next DMA overwrite
  }

  // epilogue: relu(acc + b1) -> split -> inter (sorted rows)
#pragma unroll
  for (int n = 0; n < 4; ++n) {
    const int gcol = n0 + wn * 64 + n * 16 + lr;
    const float bias = b1[(size_t)e * F + gcol];
#pragma unroll
    for (int m = 0; m < 4; ++m) {
#pragma unroll
      for (int j = 0; j < 4; ++j) {
        const int lm = m0 + wm * 64 + m * 16 + lg * 4 + j;
        if (lm >= count) continue;
        const float v = fmaxf(acc[m][n][j] + bias, 0.f);
        const u16 hi = f2bf(v);
        const size_t o = (size_t)(base + lm) * F + gcol;
        ih[o] = hi;
        if constexpr (USE_IL) il[o] = f2bf(v - bf2f(hi));
      }
    }
  }
}

// ---------------- Grouped bf16x3 MFMA GEMM2 (m97-style gload_lds staging) ----------------
// out[t] = inter_sorted @ W2T_e^T + b2_e + x[t]
template <bool USE_IL>
__global__ __launch_bounds__(256, 3)
void gemm2_kernel(const u16* __restrict__ ih, const u16* __restrict__ il,
                  const u16* __restrict__ wth, const u16* __restrict__ wtl,
                  const float* __restrict__ b2, const float* __restrict__ x,
                  float* __restrict__ out,
                  const int* __restrict__ cnt, const int* __restrict__ off,
                  const int* __restrict__ list,
                  const int* __restrict__ ntiles, const int* __restrict__ tab,
                  int D, int F, int gxl, int nwg) {
  const int f = xcd_swz(blockIdx.x, nwg);
  const int tile = f >> gxl;
  if (tile >= *ntiles) return;
  const int te = tab[tile];
  const int e = te >> 16;
  const int m0 = (te & 0xffff) << 7;
  const int n0 = (f & ((1 << gxl) - 1)) << 7;
  const int count = cnt[e];
  const int base = off[e];
  const int tid = threadIdx.x;

  __shared__ u16 Ah[128][32];
  __shared__ u16 Al[128][32];
  __shared__ u16 Bh[128][32];
  __shared__ u16 Bl[128][32];

  const int l = tid & 63, w = tid >> 6;
  const int row0 = w * 16 + (l >> 2);
  const int row1 = (4 + w) * 16 + (l >> 2);
  const int seg = (l & 3) * 8;

  const size_t ar0 = (size_t)(base + min(m0 + row0, count - 1));
  const size_t ar1 = (size_t)(base + min(m0 + row1, count - 1));
  const size_t bn0 = (size_t)e * D + n0;  // global row in W2T [5D][F]
  const size_t br0 = (bn0 + row0) * (size_t)F;
  const size_t br1 = (bn0 + row1) * (size_t)F;

  const int lane = tid & 63;
  const int wid = tid >> 6;
  const int wm = wid >> 1, wn = wid & 1;
  const int lr = lane & 15, lg = lane >> 4;

  int aoff[4], boff[4];
#pragma unroll
  for (int m = 0; m < 4; ++m) aoff[m] = (wm * 64 + m * 16 + lr) * 32 + lg * 8;
#pragma unroll
  for (int n = 0; n < 4; ++n) boff[n] = (wn * 64 + n * 16 + lr) * 32 + lg * 8;

  f32x4 acc[4][4];
#pragma unroll
  for (int m = 0; m < 4; ++m)
#pragma unroll
    for (int n = 0; n < 4; ++n) acc[m][n] = (f32x4){0.f, 0.f, 0.f, 0.f};

  for (int k0 = 0; k0 < F; k0 += 32) {
    gload_lds16(ih + ar0 * F + k0 + seg, &Ah[row0][seg]);
    gload_lds16(ih + ar1 * F + k0 + seg, &Ah[row1][seg]);
    if constexpr (USE_IL) {
      gload_lds16(il + ar0 * F + k0 + seg, &Al[row0][seg]);
      gload_lds16(il + ar1 * F + k0 + seg, &Al[row1][seg]);
    }
    gload_lds16(wth + br0 + k0 + seg, &Bh[row0][seg]);
    gload_lds16(wth + br1 + k0 + seg, &Bh[row1][seg]);
    gload_lds16(wtl + br0 + k0 + seg, &Bl[row0][seg]);
    gload_lds16(wtl + br1 + k0 + seg, &Bl[row1][seg]);
    __syncthreads();

    bf16x8 ah[4], al[4], bh[4], bl[4];
#pragma unroll
    for (int m = 0; m < 4; ++m) {
      ah[m] = *reinterpret_cast<const bf16x8*>(&Ah[0][0] + aoff[m]);
      if constexpr (USE_IL) al[m] = *reinterpret_cast<const bf16x8*>(&Al[0][0] + aoff[m]);
    }
#pragma unroll
    for (int n = 0; n < 4; ++n) {
      bh[n] = *reinterpret_cast<const bf16x8*>(&Bh[0][0] + boff[n]);
      bl[n] = *reinterpret_cast<const bf16x8*>(&Bl[0][0] + boff[n]);
    }
#pragma unroll
    for (int m = 0; m < 4; ++m)
#pragma unroll
      for (int n = 0; n < 4; ++n) {
        acc[m][n] = __builtin_amdgcn_mfma_f32_16x16x32_bf16(ah[m], bh[n], acc[m][n], 0, 0, 0);
        acc[m][n] = __builtin_amdgcn_mfma_f32_16x16x32_bf16(ah[m], bl[n], acc[m][n], 0, 0, 0);
        if constexpr (USE_IL)
          acc[m][n] = __builtin_amdgcn_mfma_f32_16x16x32_bf16(al[m], bh[n], acc[m][n], 0, 0, 0);
      }
    __syncthreads();
  }

  int trow[4][4];
#pragma unroll
  for (int m = 0; m < 4; ++m)
#pragma unroll
    for (int j = 0; j < 4; ++j) {
      const int lm = m0 + wm * 64 + m * 16 + lg * 4 + j;
      trow[m][j] = (lm < count) ? list[base + lm] : -1;
    }

#pragma unroll
  for (int n = 0; n < 4; ++n) {
    const int gcol = n0 + wn * 64 + n * 16 + lr;
    const float bias = b2[(size_t)e * D + gcol];
#pragma unroll
    for (int m = 0; m < 4; ++m) {
#pragma unroll
      for (int j = 0; j < 4; ++j) {
        const int t = trow[m][j];
        if (t < 0) continue;
        const size_t o = (size_t)t * D + gcol;
        out[o] = acc[m][n][j] + bias + x[o];
      }
    }
  }
}

extern "C" void kernel_launch(void* const* d_in, const int* in_sizes, int n_in,
                              void* d_out, int out_size, void* d_ws, size_t ws_size,
                              hipStream_t stream) {
  const float* x     = (const float*)d_in[0];
  const int*   code  = (const int*)d_in[1];
  const float* W1    = (const float*)d_in[2];
  const float* b1    = (const float*)d_in[3];
  const float* W2    = (const float*)d_in[4];
  const float* b2    = (const float*)d_in[5];
  const float* gamma = (const float*)d_in[6];
  const float* beta  = (const float*)d_in[7];
  const int T = in_sizes[1];
  const int D = in_sizes[6];
  const int F = in_sizes[3] / NEXP;
  float* out = (float*)d_out;

  // ws layout: [0,96B) cnt/off/fill; ntiles @96; tab @512 (<=1KiB);
  // list @4KiB, rank @256KiB (T*4 = 64KiB each);
  // wt hi @1MiB, wt lo @21MiB (20MiB each; W1T buffers reused for W2T — stream-serialized);
  // inter hi @41MiB (64MiB); inter lo @105MiB (64MiB, only if it fits).
  char* ws = (char*)d_ws;
  const size_t MiB = 1u << 20;
  int* cnt    = (int*)ws;
  int* off    = cnt + 8;
  int* fill   = cnt + 16;
  int* ntiles = (int*)(ws + 96);
  int* tab    = (int*)(ws + 512);
  int* list   = (int*)(ws + 4096);
  int* rank   = (int*)(ws + 256 * 1024);
  u16* wth = (u16*)(ws + 1 * MiB);
  u16* wtl = (u16*)(ws + 21 * MiB);
  u16* ih  = (u16*)(ws + 41 * MiB);
  u16* il  = (u16*)(ws + 105 * MiB);
  const bool use_il = ws_size >= 169 * MiB;  // fallback: bf16-hi-only inter

  // h (hi/lo bf16) lives in d_out (exactly T*D*4 B); consumed by gemm1,
  // then gemm2 overwrites d_out with the final result.
  u16* hh = (u16*)d_out;
  u16* hl = hh + (size_t)T * D;

  hipMemsetAsync(d_ws, 0, 256, stream);
  const int tb = (T + 255) / 256;
  count_kernel<<<tb, 256, 0, stream>>>(code, cnt, T);
  offsets_kernel<<<1, 64, 0, stream>>>(cnt, off, ntiles, tab);
  scatter_kernel<<<tb, 256, 0, stream>>>(code, off, fill, list, rank, T);

  ln_kernel<<<T, D / 4, 0, stream>>>(x, gamma, beta, rank, hh, hl, D);

  // W1 [D][5F] -> W1T [5F][D]
  transpose_split_kernel<<<dim3((NEXP * F) / 32, D / 32), dim3(32, 8), 0, stream>>>(
      W1, wth, wtl, D, NEXP * F);

  // Compact grids: MAXT = max possible m-tiles = ceil(T/128)+NEXP-1
  const int MAXT = (T + 127) / 128 + NEXP - 1;
  const int gx1 = F / 128, gx1l = 31 - __builtin_clz(gx1);
  const int nwg1 = MAXT * gx1;
  if (use_il)
    gemm1_kernel<true><<<nwg1, 256, 0, stream>>>(hh, hl, wth, wtl, b1, ih, il,
                                                 cnt, off, ntiles, tab, D, F, gx1l, nwg1);
  else
    gemm1_kernel<false><<<nwg1, 256, 0, stream>>>(hh, hl, wth, wtl, b1, ih, ih,
                                                  cnt, off, ntiles, tab, D, F, gx1l, nwg1);

  // W2 [F][5D] -> W2T [5D][F] (reuses W1T buffers; gemm1 already done in stream order)
  transpose_split_kernel<<<dim3((NEXP * D) / 32, F / 32), dim3(32, 8), 0, stream>>>(
      W2, wth, wtl, F, NEXP * D);

  const int gx2 = D / 128, gx2l = 31 - __builtin_clz(gx2);
  const int nwg2 = MAXT * gx2;
  if (use_il)
    gemm2_kernel<true><<<nwg2, 256, 0, stream>>>(ih, il, wth, wtl, b2, x, out,
                                                 cnt, off, list, ntiles, tab, D, F, gx2l, nwg2);
  else
    gemm2_kernel<false><<<nwg2, 256, 0, stream>>>(ih, ih, wth, wtl, b2, x, out,
                                                  cnt, off, list, ntiles, tab, D, F, gx2l, nwg2);
}